// Round 4
// baseline (96.652 us; speedup 1.0000x reference)
//
#include <hip/hip_runtime.h>
#include <hip/hip_bf16.h>

typedef __attribute__((ext_vector_type(8))) short bf16x8;
typedef __attribute__((ext_vector_type(4))) short bf16x4;
typedef __attribute__((ext_vector_type(4))) float f32x4;

#define LEAKY(v) ((v) >= 0.f ? (v) : 0.1f * (v))

constexpr int Q = 16384, S = 16384, KNN = 32, F = 64, O = 64;
constexpr int NEDGE = Q * KNN;
constexpr int QB = 8;                   // q's per main block
constexpr int EB = 256;                 // edges per block
constexpr int GD = Q / QB;              // 2048 main blocks
constexpr int GH = 128;                 // k_hsq blocks (128 s each)
constexpr int FP = 72;                  // padded bf16 H row (144B stride)
constexpr float EPSV = 1e-5f;

// workspace byte offsets
constexpr size_t CNT_OFF  = 0;                                    // S ints
constexpr size_t CTR_OFF  = 65536;                                // ticket counters (64B)
constexpr size_t P0_OFF   = 65600;                                // GH*128 f32
constexpr size_t ST0_OFF  = P0_OFF + (size_t)GH * 128 * 4;        // 128 f32
constexpr size_t ZMIN_OFF = ST0_OFF + 512;                        // Q*O f32
constexpr size_t P1_OFF   = ZMIN_OFF + (size_t)Q * O * 4;         // GD*128 f32
constexpr size_t ST1_OFF  = P1_OFF + (size_t)GD * 128 * 4;        // 128 f32
constexpr size_t W0F_OFF  = ST1_OFF + 512;                        // 8*64*8 bf16
constexpr size_t W1F_OFF  = W0F_OFF + 8192;                       // 24*64*8 bf16

__device__ __forceinline__ short f2bf(float f) {
  __hip_bfloat16 h = __float2bfloat16(f);
  short r; __builtin_memcpy(&r, &h, 2); return r;
}

// ---------------- fused: weight fragment prep (blocks 0-7) + histogram (blocks 8+) -------
__global__ void k_prep_hist(const float* __restrict__ w0g, const float* __restrict__ w1g,
                            short* __restrict__ w0f, short* __restrict__ w1f,
                            const int* __restrict__ inds, int* __restrict__ cnt) {
  if (blockIdx.x < 8) {
    const int t = blockIdx.x * 256 + threadIdx.x;   // 2048 entries
    const int fa = t >> 6, ln = t & 63;
    const int l4 = ln >> 4, l15 = ln & 15;
    if (fa < 8) {
      // W0 A-operand frags: A[m=o][k=f]; frag (mt,kk): o=16mt+l15, f=32kk+8l4
      const int mt = fa >> 1, kk = fa & 1;
      const int o = 16 * mt + l15, f = 32 * kk + 8 * l4;
      const float* src = w0g + o * 64 + f;
      bf16x8 pk;
#pragma unroll
      for (int j = 0; j < 8; ++j) pk[j] = f2bf(src[j]);
      *(bf16x8*)&w0f[t * 8] = pk;
    } else {
      // W1 B-operand frags: B[k=op][n=c], c=i*64+o; frag nt=i*4+b: o=16b+l15, op=32kk+8l4
      const int fb = fa - 8;                 // 0..23
      const int nt = fb >> 1, kk = fb & 1;
      const int i = nt >> 2, b = nt & 3;
      const int o = 16 * b + l15, op = 32 * kk + 8 * l4;
      const float* src = w1g + (o * 3 + i) * 64 + op;
      bf16x8 pk;
#pragma unroll
      for (int j = 0; j < 8; ++j) pk[j] = f2bf(src[j]);
      *(bf16x8*)&w1f[(fb * 64 + ln) * 8] = pk;
    }
  } else {
    const int i = (blockIdx.x - 8) * 256 + threadIdx.x;   // 512 blocks cover NEDGE/4
    const int4 v = ((const int4*)inds)[i];
    if (v.x < S) atomicAdd(&cnt[v.x], 1);
    if (v.y < S) atomicAdd(&cnt[v.y], 1);
    if (v.z < S) atomicAdd(&cnt[v.z], 1);
    if (v.w < S) atomicAdd(&cnt[v.w], 1);
  }
}

// ---------------- BN0 stats via MFMA + fused last-block reduce -> st0 ----------------
__global__ void k_hsq(const float* __restrict__ feat, const int* __restrict__ cnt,
                      const short* __restrict__ w0f, float* __restrict__ p0,
                      int* __restrict__ ctr, const float* __restrict__ g0,
                      const float* __restrict__ b0, float* __restrict__ st0) {
  __shared__ float sred[4][2][64];
  __shared__ int isLast;
  const int t = threadIdx.x, blk = blockIdx.x;
  const int wv = t >> 6, ln = t & 63, l4 = ln >> 4, l15 = ln & 15;

  const bf16x8* w0v = (const bf16x8*)w0f;
  bf16x8 w0a[8];
#pragma unroll
  for (int fa = 0; fa < 8; ++fa) w0a[fa] = w0v[fa * 64 + ln];

  float hs[4][4], hq[4][4];
#pragma unroll
  for (int mt = 0; mt < 4; ++mt)
#pragma unroll
    for (int r = 0; r < 4; ++r) { hs[mt][r] = 0.f; hq[mt][r] = 0.f; }

#pragma unroll
  for (int tile = 0; tile < 2; ++tile) {
    const int s0 = blk * 128 + (wv * 2 + tile) * 16;
    const float wc = (float)cnt[s0 + l15];
    const float4* fr = (const float4*)(feat + (size_t)(s0 + l15) * 64);
    float4 a = fr[2 * l4], b = fr[2 * l4 + 1];
    float4 c = fr[8 + 2 * l4], d = fr[9 + 2 * l4];
    bf16x8 y0, y1;
    y0[0] = f2bf(a.x); y0[1] = f2bf(a.y); y0[2] = f2bf(a.z); y0[3] = f2bf(a.w);
    y0[4] = f2bf(b.x); y0[5] = f2bf(b.y); y0[6] = f2bf(b.z); y0[7] = f2bf(b.w);
    y1[0] = f2bf(c.x); y1[1] = f2bf(c.y); y1[2] = f2bf(c.z); y1[3] = f2bf(c.w);
    y1[4] = f2bf(d.x); y1[5] = f2bf(d.y); y1[6] = f2bf(d.z); y1[7] = f2bf(d.w);
#pragma unroll
    for (int mt = 0; mt < 4; ++mt) {
      f32x4 acc = {0.f, 0.f, 0.f, 0.f};
      acc = __builtin_amdgcn_mfma_f32_16x16x32_bf16(w0a[2 * mt], y0, acc, 0, 0, 0);
      acc = __builtin_amdgcn_mfma_f32_16x16x32_bf16(w0a[2 * mt + 1], y1, acc, 0, 0, 0);
#pragma unroll
      for (int r = 0; r < 4; ++r) {
        float h = acc[r];
        hs[mt][r] += wc * h;
        hq[mt][r] += wc * h * h;
      }
    }
  }
#pragma unroll
  for (int mt = 0; mt < 4; ++mt)
#pragma unroll
    for (int r = 0; r < 4; ++r) {
      float s = hs[mt][r], q = hq[mt][r];
#pragma unroll
      for (int d = 1; d < 16; d <<= 1) { s += __shfl_xor(s, d); q += __shfl_xor(q, d); }
      hs[mt][r] = s; hq[mt][r] = q;
    }
  if (l15 == 0) {
#pragma unroll
    for (int mt = 0; mt < 4; ++mt)
#pragma unroll
      for (int r = 0; r < 4; ++r) {
        const int o = 16 * mt + 4 * l4 + r;
        sred[wv][0][o] = hs[mt][r];
        sred[wv][1][o] = hq[mt][r];
      }
  }
  __syncthreads();
  if (t < 128) {
    const int qq = t >> 6, o = t & 63;
    p0[(size_t)blk * 128 + t] =
        sred[0][qq][o] + sred[1][qq][o] + sred[2][qq][o] + sred[3][qq][o];
  }
  // last-block reduction -> st0 (deterministic: fixed read order)
  __syncthreads();
  __threadfence();
  if (t == 0) isLast = (atomicAdd(&ctr[0], 1) == GH - 1);
  __syncthreads();
  if (isLast) {
    __threadfence();
    if (t < O) {
      float s = 0.f, q = 0.f;
      for (int b = 0; b < GH; ++b) {
        s += p0[(size_t)b * 128 + t];
        q += p0[(size_t)b * 128 + 64 + t];
      }
      const float invN = 1.f / (float)NEDGE;
      float mean = s * invN;
      float var = q * invN - mean * mean;
      float sc = g0[t] * rsqrtf(var + EPSV);
      st0[t] = sc;
      st0[O + t] = b0[t] - mean * sc;
    }
  }
}

// ---------------- main MFMA pass: direct-gather Y, LDS only for H + x ----------------
__launch_bounds__(256, 4)
__global__ void k_main(const float* __restrict__ qpts, const float* __restrict__ spts,
                       const float* __restrict__ feat, const int* __restrict__ inds,
                       const short* __restrict__ w0f, const short* __restrict__ w1f,
                       const float* __restrict__ st0,
                       float* __restrict__ zmax, float* __restrict__ zmin,
                       float* __restrict__ p1) {
  __shared__ __align__(16) short hbuf[EB * FP];   // H only, [e][72] bf16
  __shared__ __align__(16) float xs[3 * EB];      // x per edge; first 512 reused as swred

  const int t = threadIdx.x, blk = blockIdx.x;
  const int wv = t >> 6, ln = t & 63, l4 = ln >> 4, l15 = ln & 15;
  const int ebase = blk * EB;

  // ---- stage x (wave-local rows; same-wave DS ordering, no barrier needed)
  {
    const int e = t;
    const int idx = inds[ebase + e];
    const int q = blk * QB + (e >> 5);
    float x0 = 0.f, x1 = 0.f, x2 = 0.f;
    if (idx < S) {
      x0 = spts[idx * 3 + 0] - qpts[q * 3 + 0];
      x1 = spts[idx * 3 + 1] - qpts[q * 3 + 1];
      x2 = spts[idx * 3 + 2] - qpts[q * 3 + 2];
    }
    xs[0 * EB + e] = x0; xs[1 * EB + e] = x1; xs[2 * EB + e] = x2;
  }

  // BN0 scale/shift regs: o = 16mt + 4*l4 + r
  float scr[4][4], shr[4][4];
#pragma unroll
  for (int mt = 0; mt < 4; ++mt)
#pragma unroll
    for (int r = 0; r < 4; ++r) {
      int o = 16 * mt + 4 * l4 + r;
      scr[mt][r] = st0[o]; shr[mt][r] = st0[O + o];
    }

  // W0 A-frags (L2-hot, coalesced)
  const bf16x8* w0v = (const bf16x8*)w0f;
  bf16x8 w0a[8];
#pragma unroll
  for (int fa = 0; fa < 8; ++fa) w0a[fa] = w0v[fa * 64 + ln];

  // ---- Phase A: per e-tile, gather Y frags straight from feat; H -> LDS
#pragma unroll
  for (int nt = 0; nt < 4; ++nt) {
    const int erow = wv * 64 + nt * 16 + l15;
    const int idx = inds[ebase + erow];
    bf16x8 y0, y1;
    if (idx < S) {
      const float* fr = feat + (size_t)idx * F + 8 * l4;
      f32x4 a = *(const f32x4*)(fr);
      f32x4 b = *(const f32x4*)(fr + 4);
      f32x4 c = *(const f32x4*)(fr + 32);
      f32x4 d = *(const f32x4*)(fr + 36);
      y0[0] = f2bf(a[0]); y0[1] = f2bf(a[1]); y0[2] = f2bf(a[2]); y0[3] = f2bf(a[3]);
      y0[4] = f2bf(b[0]); y0[5] = f2bf(b[1]); y0[6] = f2bf(b[2]); y0[7] = f2bf(b[3]);
      y1[0] = f2bf(c[0]); y1[1] = f2bf(c[1]); y1[2] = f2bf(c[2]); y1[3] = f2bf(c[3]);
      y1[4] = f2bf(d[0]); y1[5] = f2bf(d[1]); y1[6] = f2bf(d[2]); y1[7] = f2bf(d[3]);
    } else {
#pragma unroll
      for (int j = 0; j < 8; ++j) { y0[j] = 0; y1[j] = 0; }
    }
#pragma unroll
    for (int mt = 0; mt < 4; ++mt) {
      f32x4 acc = {0.f, 0.f, 0.f, 0.f};
      acc = __builtin_amdgcn_mfma_f32_16x16x32_bf16(w0a[2 * mt], y0, acc, 0, 0, 0);
      acc = __builtin_amdgcn_mfma_f32_16x16x32_bf16(w0a[2 * mt + 1], y1, acc, 0, 0, 0);
      bf16x4 hv;
#pragma unroll
      for (int r = 0; r < 4; ++r) {
        float v = acc[r] * scr[mt][r] + shr[mt][r];
        v = LEAKY(v);
        hv[r] = f2bf(v);
      }
      *(bf16x4*)&hbuf[erow * FP + 16 * mt + 4 * l4] = hv;
    }
  }

  // ---- Phase B operand prefetch (wave-local H rows; same-wave DS ordering)
  bf16x8 hA[4][2];
#pragma unroll
  for (int mt = 0; mt < 4; ++mt) {
    const int erow = wv * 64 + mt * 16 + l15;
    hA[mt][0] = *(const bf16x8*)&hbuf[erow * FP + 8 * l4];
    hA[mt][1] = *(const bf16x8*)&hbuf[erow * FP + 32 + 8 * l4];
  }

  const bf16x8* w1v = (const bf16x8*)w1f;
  float zmx[2][4], zmn[2][4], zs[4], zq[4];
#pragma unroll
  for (int j = 0; j < 4; ++j) {
    zs[j] = 0.f; zq[j] = 0.f;
    zmx[0][j] = -3.4e38f; zmx[1][j] = -3.4e38f;
    zmn[0][j] = 3.4e38f;  zmn[1][j] = 3.4e38f;
  }

  // ---- Phase B: D2[e][c=i*64+o] = H * W1p ; combine with x ; stats
#pragma unroll
  for (int b = 0; b < 4; ++b) {
    bf16x8 w1b[6];
#pragma unroll
    for (int i = 0; i < 3; ++i)
#pragma unroll
      for (int kk = 0; kk < 2; ++kk)
        w1b[i * 2 + kk] = w1v[(((i * 4 + b) * 2) + kk) * 64 + ln];
#pragma unroll
    for (int mt = 0; mt < 4; ++mt) {
      const int ex = wv * 64 + mt * 16 + 4 * l4;
      f32x4 z4 = {0.f, 0.f, 0.f, 0.f};
#pragma unroll
      for (int i = 0; i < 3; ++i) {
        f32x4 acc = {0.f, 0.f, 0.f, 0.f};
        acc = __builtin_amdgcn_mfma_f32_16x16x32_bf16(hA[mt][0], w1b[2 * i], acc, 0, 0, 0);
        acc = __builtin_amdgcn_mfma_f32_16x16x32_bf16(hA[mt][1], w1b[2 * i + 1], acc, 0, 0, 0);
        const f32x4 xv = *(const f32x4*)&xs[i * EB + ex];
#pragma unroll
        for (int r = 0; r < 4; ++r) z4[r] += acc[r] * xv[r];
      }
      const int qh = mt >> 1;
#pragma unroll
      for (int r = 0; r < 4; ++r) {
        float v = z4[r];
        zmx[qh][b] = fmaxf(zmx[qh][b], v);
        zmn[qh][b] = fminf(zmn[qh][b], v);
        zs[b] += v; zq[b] += v * v;
      }
    }
  }

  // ---- cross-group (l4) reductions: lanes l, l^16, l^32 share o
#pragma unroll
  for (int qh = 0; qh < 2; ++qh)
#pragma unroll
    for (int b = 0; b < 4; ++b) {
      float m = zmx[qh][b];
      m = fmaxf(m, __shfl_xor(m, 16)); m = fmaxf(m, __shfl_xor(m, 32));
      zmx[qh][b] = m;
      float n = zmn[qh][b];
      n = fminf(n, __shfl_xor(n, 16)); n = fminf(n, __shfl_xor(n, 32));
      zmn[qh][b] = n;
    }
#pragma unroll
  for (int b = 0; b < 4; ++b) {
    float s = zs[b];  s += __shfl_xor(s, 16);  s += __shfl_xor(s, 32);  zs[b] = s;
    float sq = zq[b]; sq += __shfl_xor(sq, 16); sq += __shfl_xor(sq, 32); zq[b] = sq;
  }

  if (l4 == 0) {
#pragma unroll
    for (int qh = 0; qh < 2; ++qh) {
      const int q = blk * QB + wv * 2 + qh;
#pragma unroll
      for (int b = 0; b < 4; ++b) {
        zmax[(size_t)q * O + 16 * b + l15] = zmx[qh][b];
        zmin[(size_t)q * O + 16 * b + l15] = zmn[qh][b];
      }
    }
  }

  // ---- block sum partials: reuse xs[0..511] as swred (barrier guards the union)
  __syncthreads();
  if (l4 == 0) {
#pragma unroll
    for (int b = 0; b < 4; ++b) {
      xs[wv * 128 + 16 * b + l15] = zs[b];
      xs[wv * 128 + 64 + 16 * b + l15] = zq[b];
    }
  }
  __syncthreads();
  if (t < 128)
    p1[(size_t)blk * 128 + t] = xs[t] + xs[128 + t] + xs[256 + t] + xs[384 + t];
}

// ---------------- reduce z stats + BN1 scale/shift (fused) ----------------
__global__ void k_red1(const float* __restrict__ p1, const float* __restrict__ g1,
                       const float* __restrict__ b1, float* __restrict__ st1) {
  __shared__ float rs[256], rq[256];
  const int o = blockIdx.x, t = threadIdx.x;
  float s = 0.f, q = 0.f;
  for (int r = t; r < GD; r += 256) {
    s += p1[(size_t)r * 128 + o];
    q += p1[(size_t)r * 128 + 64 + o];
  }
  rs[t] = s; rq[t] = q;
  __syncthreads();
  for (int off = 128; off > 0; off >>= 1) {
    if (t < off) { rs[t] += rs[t + off]; rq[t] += rq[t + off]; }
    __syncthreads();
  }
  if (t == 0) {
    const float invN = 1.f / (float)NEDGE;
    float mean = rs[0] * invN;
    float var = rq[0] * invN - mean * mean;
    float sc = g1[o] * rsqrtf(var + EPSV);
    st1[o] = sc;
    st1[O + o] = b1[o] - mean * sc;
  }
}

// ---------------- finalize: pick max/min by scale sign, affine + leaky ----------------
__global__ void k_final(const float* __restrict__ st1, const float* __restrict__ zmin,
                        float* __restrict__ out) {
  int i = blockIdx.x * blockDim.x + threadIdx.x;
  if (i < Q * O) {
    int o = i & 63;
    float sc = st1[o], sh = st1[O + o];
    float base = (sc >= 0.f) ? out[i] : zmin[i];   // out currently holds zmax
    float v = base * sc + sh;
    out[i] = LEAKY(v);
  }
}

extern "C" void kernel_launch(void* const* d_in, const int* in_sizes, int n_in,
                              void* d_out, int out_size, void* d_ws, size_t ws_size,
                              hipStream_t stream) {
  const float* qpts = (const float*)d_in[0];
  const float* spts = (const float*)d_in[1];
  const float* feat = (const float*)d_in[2];
  const int*   inds = (const int*)d_in[3];
  const float* w0   = (const float*)d_in[4];
  const float* g0   = (const float*)d_in[5];
  const float* b0   = (const float*)d_in[6];
  const float* w1   = (const float*)d_in[7];
  const float* g1   = (const float*)d_in[8];
  const float* b1   = (const float*)d_in[9];
  float* out = (float*)d_out;

  char* ws = (char*)d_ws;
  int*   cnt  = (int*)(ws + CNT_OFF);
  int*   ctr  = (int*)(ws + CTR_OFF);
  float* p0   = (float*)(ws + P0_OFF);
  float* st0  = (float*)(ws + ST0_OFF);
  float* zmin = (float*)(ws + ZMIN_OFF);
  float* p1   = (float*)(ws + P1_OFF);
  float* st1  = (float*)(ws + ST1_OFF);
  short* w0f  = (short*)(ws + W0F_OFF);
  short* w1f  = (short*)(ws + W1F_OFF);

  hipMemsetAsync(ws, 0, CTR_OFF + 64, stream);   // cnt + ticket counters
  k_prep_hist<<<520, 256, 0, stream>>>(w0, w1, w0f, w1f, inds, cnt);
  k_hsq<<<GH, 256, 0, stream>>>(feat, cnt, w0f, p0, ctr, g0, b0, st0);
  k_main<<<GD, 256, 0, stream>>>(qpts, spts, feat, inds, w0f, w1f, st0, out, zmin, p1);
  k_red1<<<64, 256, 0, stream>>>(p1, g1, b1, st1);
  k_final<<<(Q * O) / 256, 256, 0, stream>>>(st1, zmin, out);
}

// Round 5
// 94.653 us; speedup vs baseline: 1.0211x; 1.0211x over previous
//
#include <hip/hip_runtime.h>
#include <hip/hip_bf16.h>

typedef __attribute__((ext_vector_type(8))) short bf16x8;
typedef __attribute__((ext_vector_type(4))) short bf16x4;
typedef __attribute__((ext_vector_type(4))) float f32x4;

#define LEAKY(v) ((v) >= 0.f ? (v) : 0.1f * (v))

constexpr int Q = 16384, S = 16384, KNN = 32, F = 64, O = 64;
constexpr int NEDGE = Q * KNN;
constexpr int QB = 8;                   // q's per main block
constexpr int EB = 256;                 // edges per block
constexpr int GD = Q / QB;              // 2048 main blocks
constexpr int GH = 128;                 // k_hsq blocks (128 s each)
constexpr int FP = 72;                  // padded bf16 H row (144B stride)
constexpr float EPSV = 1e-5f;

// workspace byte offsets
constexpr size_t CNT_OFF  = 0;                                    // S ints
constexpr size_t CTR_OFF  = 65536;                                // ticket counters (64B)
constexpr size_t P0_OFF   = 65600;                                // GH*128 f32
constexpr size_t ST0_OFF  = P0_OFF + (size_t)GH * 128 * 4;        // 128 f32
constexpr size_t ZMIN_OFF = ST0_OFF + 512;                        // Q*O f32
constexpr size_t P1_OFF   = ZMIN_OFF + (size_t)Q * O * 4;         // GD*128 f32
constexpr size_t ST1_OFF  = P1_OFF + (size_t)GD * 128 * 4;        // 128 f32
constexpr size_t W0F_OFF  = ST1_OFF + 512;                        // 8*64*8 bf16
constexpr size_t W1F_OFF  = W0F_OFF + 8192;                       // 24*64*8 bf16

__device__ __forceinline__ short f2bf(float f) {
  __hip_bfloat16 h = __float2bfloat16(f);
  short r; __builtin_memcpy(&r, &h, 2); return r;
}

// ---------------- fused: weight fragment prep (blocks 0-7) + histogram (blocks 8+) -------
__global__ void k_prep_hist(const float* __restrict__ w0g, const float* __restrict__ w1g,
                            short* __restrict__ w0f, short* __restrict__ w1f,
                            const int* __restrict__ inds, int* __restrict__ cnt) {
  if (blockIdx.x < 8) {
    const int t = blockIdx.x * 256 + threadIdx.x;   // 2048 entries
    const int fa = t >> 6, ln = t & 63;
    const int l4 = ln >> 4, l15 = ln & 15;
    if (fa < 8) {
      // W0 A-operand frags: A[m=o][k=f]; frag (mt,kk): o=16mt+l15, f=32kk+8l4
      const int mt = fa >> 1, kk = fa & 1;
      const int o = 16 * mt + l15, f = 32 * kk + 8 * l4;
      const float* src = w0g + o * 64 + f;
      bf16x8 pk;
#pragma unroll
      for (int j = 0; j < 8; ++j) pk[j] = f2bf(src[j]);
      *(bf16x8*)&w0f[t * 8] = pk;
    } else {
      // W1 B-operand frags: B[k=op][n=c], c=i*64+o; frag nt=i*4+b: o=16b+l15, op=32kk+8l4
      const int fb = fa - 8;                 // 0..23
      const int nt = fb >> 1, kk = fb & 1;
      const int i = nt >> 2, b = nt & 3;
      const int o = 16 * b + l15, op = 32 * kk + 8 * l4;
      const float* src = w1g + (o * 3 + i) * 64 + op;
      bf16x8 pk;
#pragma unroll
      for (int j = 0; j < 8; ++j) pk[j] = f2bf(src[j]);
      *(bf16x8*)&w1f[(fb * 64 + ln) * 8] = pk;
    }
  } else {
    const int i = (blockIdx.x - 8) * 256 + threadIdx.x;   // 512 blocks cover NEDGE/4
    const int4 v = ((const int4*)inds)[i];
    if (v.x < S) atomicAdd(&cnt[v.x], 1);
    if (v.y < S) atomicAdd(&cnt[v.y], 1);
    if (v.z < S) atomicAdd(&cnt[v.z], 1);
    if (v.w < S) atomicAdd(&cnt[v.w], 1);
  }
}

// ---------------- BN0 stats via MFMA + fused last-block reduce -> st0 ----------------
__global__ void k_hsq(const float* __restrict__ feat, const int* __restrict__ cnt,
                      const short* __restrict__ w0f, float* __restrict__ p0,
                      int* __restrict__ ctr, const float* __restrict__ g0,
                      const float* __restrict__ b0, float* __restrict__ st0) {
  __shared__ float sred[4][2][64];
  __shared__ int isLast;
  const int t = threadIdx.x, blk = blockIdx.x;
  const int wv = t >> 6, ln = t & 63, l4 = ln >> 4, l15 = ln & 15;

  const bf16x8* w0v = (const bf16x8*)w0f;
  bf16x8 w0a[8];
#pragma unroll
  for (int fa = 0; fa < 8; ++fa) w0a[fa] = w0v[fa * 64 + ln];

  float hs[4][4], hq[4][4];
#pragma unroll
  for (int mt = 0; mt < 4; ++mt)
#pragma unroll
    for (int r = 0; r < 4; ++r) { hs[mt][r] = 0.f; hq[mt][r] = 0.f; }

#pragma unroll
  for (int tile = 0; tile < 2; ++tile) {
    const int s0 = blk * 128 + (wv * 2 + tile) * 16;
    const float wc = (float)cnt[s0 + l15];
    const float4* fr = (const float4*)(feat + (size_t)(s0 + l15) * 64);
    float4 a = fr[2 * l4], b = fr[2 * l4 + 1];
    float4 c = fr[8 + 2 * l4], d = fr[9 + 2 * l4];
    bf16x8 y0, y1;
    y0[0] = f2bf(a.x); y0[1] = f2bf(a.y); y0[2] = f2bf(a.z); y0[3] = f2bf(a.w);
    y0[4] = f2bf(b.x); y0[5] = f2bf(b.y); y0[6] = f2bf(b.z); y0[7] = f2bf(b.w);
    y1[0] = f2bf(c.x); y1[1] = f2bf(c.y); y1[2] = f2bf(c.z); y1[3] = f2bf(c.w);
    y1[4] = f2bf(d.x); y1[5] = f2bf(d.y); y1[6] = f2bf(d.z); y1[7] = f2bf(d.w);
#pragma unroll
    for (int mt = 0; mt < 4; ++mt) {
      f32x4 acc = {0.f, 0.f, 0.f, 0.f};
      acc = __builtin_amdgcn_mfma_f32_16x16x32_bf16(w0a[2 * mt], y0, acc, 0, 0, 0);
      acc = __builtin_amdgcn_mfma_f32_16x16x32_bf16(w0a[2 * mt + 1], y1, acc, 0, 0, 0);
#pragma unroll
      for (int r = 0; r < 4; ++r) {
        float h = acc[r];
        hs[mt][r] += wc * h;
        hq[mt][r] += wc * h * h;
      }
    }
  }
#pragma unroll
  for (int mt = 0; mt < 4; ++mt)
#pragma unroll
    for (int r = 0; r < 4; ++r) {
      float s = hs[mt][r], q = hq[mt][r];
#pragma unroll
      for (int d = 1; d < 16; d <<= 1) { s += __shfl_xor(s, d); q += __shfl_xor(q, d); }
      hs[mt][r] = s; hq[mt][r] = q;
    }
  if (l15 == 0) {
#pragma unroll
    for (int mt = 0; mt < 4; ++mt)
#pragma unroll
      for (int r = 0; r < 4; ++r) {
        const int o = 16 * mt + 4 * l4 + r;
        sred[wv][0][o] = hs[mt][r];
        sred[wv][1][o] = hq[mt][r];
      }
  }
  __syncthreads();
  if (t < 128) {
    const int qq = t >> 6, o = t & 63;
    p0[(size_t)blk * 128 + t] =
        sred[0][qq][o] + sred[1][qq][o] + sred[2][qq][o] + sred[3][qq][o];
  }
  // last-block reduction -> st0 (deterministic: fixed read order)
  __syncthreads();
  __threadfence();
  if (t == 0) isLast = (atomicAdd(&ctr[0], 1) == GH - 1);
  __syncthreads();
  if (isLast) {
    __threadfence();
    if (t < O) {
      float s = 0.f, q = 0.f;
      for (int b = 0; b < GH; ++b) {
        s += p0[(size_t)b * 128 + t];
        q += p0[(size_t)b * 128 + 64 + t];
      }
      const float invN = 1.f / (float)NEDGE;
      float mean = s * invN;
      float var = q * invN - mean * mean;
      float sc = g0[t] * rsqrtf(var + EPSV);
      st0[t] = sc;
      st0[O + t] = b0[t] - mean * sc;
    }
  }
}

// ---------------- main MFMA pass: direct-gather Y, LDS only for H + x ----------------
__launch_bounds__(256, 3)
__global__ void k_main(const float* __restrict__ qpts, const float* __restrict__ spts,
                       const float* __restrict__ feat, const int* __restrict__ inds,
                       const short* __restrict__ w0f, const short* __restrict__ w1f,
                       const float* __restrict__ st0,
                       float* __restrict__ zmax, float* __restrict__ zmin,
                       float* __restrict__ p1) {
  __shared__ __align__(16) short hbuf[EB * FP];   // H only, [e][72] bf16
  __shared__ __align__(16) float xs[3 * EB];      // x per edge; first 512 reused as swred

  const int t = threadIdx.x, blk = blockIdx.x;
  const int wv = t >> 6, ln = t & 63, l4 = ln >> 4, l15 = ln & 15;
  const int ebase = blk * EB;

  // ---- stage x (wave-local rows; same-wave DS ordering, no barrier needed)
  {
    const int e = t;
    const int idx = inds[ebase + e];
    const int q = blk * QB + (e >> 5);
    float x0 = 0.f, x1 = 0.f, x2 = 0.f;
    if (idx < S) {
      x0 = spts[idx * 3 + 0] - qpts[q * 3 + 0];
      x1 = spts[idx * 3 + 1] - qpts[q * 3 + 1];
      x2 = spts[idx * 3 + 2] - qpts[q * 3 + 2];
    }
    xs[0 * EB + e] = x0; xs[1 * EB + e] = x1; xs[2 * EB + e] = x2;
  }

  // BN0 scale/shift regs: o = 16mt + 4*l4 + r
  float scr[4][4], shr[4][4];
#pragma unroll
  for (int mt = 0; mt < 4; ++mt)
#pragma unroll
    for (int r = 0; r < 4; ++r) {
      int o = 16 * mt + 4 * l4 + r;
      scr[mt][r] = st0[o]; shr[mt][r] = st0[O + o];
    }

  // W0 A-frags (L2-hot, coalesced)
  const bf16x8* w0v = (const bf16x8*)w0f;
  bf16x8 w0a[8];
#pragma unroll
  for (int fa = 0; fa < 8; ++fa) w0a[fa] = w0v[fa * 64 + ln];

  // ---- Phase A: per e-tile, gather Y frags straight from feat; H -> LDS
#pragma unroll
  for (int nt = 0; nt < 4; ++nt) {
    const int erow = wv * 64 + nt * 16 + l15;
    const int idx = inds[ebase + erow];
    bf16x8 y0, y1;
    if (idx < S) {
      const float* fr = feat + (size_t)idx * F + 8 * l4;
      f32x4 a = *(const f32x4*)(fr);
      f32x4 b = *(const f32x4*)(fr + 4);
      f32x4 c = *(const f32x4*)(fr + 32);
      f32x4 d = *(const f32x4*)(fr + 36);
      y0[0] = f2bf(a[0]); y0[1] = f2bf(a[1]); y0[2] = f2bf(a[2]); y0[3] = f2bf(a[3]);
      y0[4] = f2bf(b[0]); y0[5] = f2bf(b[1]); y0[6] = f2bf(b[2]); y0[7] = f2bf(b[3]);
      y1[0] = f2bf(c[0]); y1[1] = f2bf(c[1]); y1[2] = f2bf(c[2]); y1[3] = f2bf(c[3]);
      y1[4] = f2bf(d[0]); y1[5] = f2bf(d[1]); y1[6] = f2bf(d[2]); y1[7] = f2bf(d[3]);
    } else {
#pragma unroll
      for (int j = 0; j < 8; ++j) { y0[j] = 0; y1[j] = 0; }
    }
#pragma unroll
    for (int mt = 0; mt < 4; ++mt) {
      f32x4 acc = {0.f, 0.f, 0.f, 0.f};
      acc = __builtin_amdgcn_mfma_f32_16x16x32_bf16(w0a[2 * mt], y0, acc, 0, 0, 0);
      acc = __builtin_amdgcn_mfma_f32_16x16x32_bf16(w0a[2 * mt + 1], y1, acc, 0, 0, 0);
      bf16x4 hv;
#pragma unroll
      for (int r = 0; r < 4; ++r) {
        float v = acc[r] * scr[mt][r] + shr[mt][r];
        v = LEAKY(v);
        hv[r] = f2bf(v);
      }
      *(bf16x4*)&hbuf[erow * FP + 16 * mt + 4 * l4] = hv;
    }
  }

  // ---- Phase B operand prefetch (wave-local H rows; same-wave DS ordering)
  bf16x8 hA[4][2];
#pragma unroll
  for (int mt = 0; mt < 4; ++mt) {
    const int erow = wv * 64 + mt * 16 + l15;
    hA[mt][0] = *(const bf16x8*)&hbuf[erow * FP + 8 * l4];
    hA[mt][1] = *(const bf16x8*)&hbuf[erow * FP + 32 + 8 * l4];
  }

  const bf16x8* w1v = (const bf16x8*)w1f;
  float zmx[2][4], zmn[2][4], zs[4], zq[4];
#pragma unroll
  for (int j = 0; j < 4; ++j) {
    zs[j] = 0.f; zq[j] = 0.f;
    zmx[0][j] = -3.4e38f; zmx[1][j] = -3.4e38f;
    zmn[0][j] = 3.4e38f;  zmn[1][j] = 3.4e38f;
  }

  // ---- Phase B: D2[e][c=i*64+o] = H * W1p ; combine with x ; stats
#pragma unroll
  for (int b = 0; b < 4; ++b) {
    bf16x8 w1b[6];
#pragma unroll
    for (int i = 0; i < 3; ++i)
#pragma unroll
      for (int kk = 0; kk < 2; ++kk)
        w1b[i * 2 + kk] = w1v[(((i * 4 + b) * 2) + kk) * 64 + ln];
#pragma unroll
    for (int mt = 0; mt < 4; ++mt) {
      const int ex = wv * 64 + mt * 16 + 4 * l4;
      f32x4 z4 = {0.f, 0.f, 0.f, 0.f};
#pragma unroll
      for (int i = 0; i < 3; ++i) {
        f32x4 acc = {0.f, 0.f, 0.f, 0.f};
        acc = __builtin_amdgcn_mfma_f32_16x16x32_bf16(hA[mt][0], w1b[2 * i], acc, 0, 0, 0);
        acc = __builtin_amdgcn_mfma_f32_16x16x32_bf16(hA[mt][1], w1b[2 * i + 1], acc, 0, 0, 0);
        const f32x4 xv = *(const f32x4*)&xs[i * EB + ex];
#pragma unroll
        for (int r = 0; r < 4; ++r) z4[r] += acc[r] * xv[r];
      }
      const int qh = mt >> 1;
#pragma unroll
      for (int r = 0; r < 4; ++r) {
        float v = z4[r];
        zmx[qh][b] = fmaxf(zmx[qh][b], v);
        zmn[qh][b] = fminf(zmn[qh][b], v);
        zs[b] += v; zq[b] += v * v;
      }
    }
  }

  // ---- cross-group (l4) reductions: lanes l, l^16, l^32 share o
#pragma unroll
  for (int qh = 0; qh < 2; ++qh)
#pragma unroll
    for (int b = 0; b < 4; ++b) {
      float m = zmx[qh][b];
      m = fmaxf(m, __shfl_xor(m, 16)); m = fmaxf(m, __shfl_xor(m, 32));
      zmx[qh][b] = m;
      float n = zmn[qh][b];
      n = fminf(n, __shfl_xor(n, 16)); n = fminf(n, __shfl_xor(n, 32));
      zmn[qh][b] = n;
    }
#pragma unroll
  for (int b = 0; b < 4; ++b) {
    float s = zs[b];  s += __shfl_xor(s, 16);  s += __shfl_xor(s, 32);  zs[b] = s;
    float sq = zq[b]; sq += __shfl_xor(sq, 16); sq += __shfl_xor(sq, 32); zq[b] = sq;
  }

  if (l4 == 0) {
#pragma unroll
    for (int qh = 0; qh < 2; ++qh) {
      const int q = blk * QB + wv * 2 + qh;
#pragma unroll
      for (int b = 0; b < 4; ++b) {
        zmax[(size_t)q * O + 16 * b + l15] = zmx[qh][b];
        zmin[(size_t)q * O + 16 * b + l15] = zmn[qh][b];
      }
    }
  }

  // ---- block sum partials: reuse xs[0..511] as swred (barrier guards the union)
  __syncthreads();
  if (l4 == 0) {
#pragma unroll
    for (int b = 0; b < 4; ++b) {
      xs[wv * 128 + 16 * b + l15] = zs[b];
      xs[wv * 128 + 64 + 16 * b + l15] = zq[b];
    }
  }
  __syncthreads();
  if (t < 128)
    p1[(size_t)blk * 128 + t] = xs[t] + xs[128 + t] + xs[256 + t] + xs[384 + t];
}

// ---------------- reduce z stats + BN1 scale/shift (fused) ----------------
__global__ void k_red1(const float* __restrict__ p1, const float* __restrict__ g1,
                       const float* __restrict__ b1, float* __restrict__ st1) {
  __shared__ float rs[256], rq[256];
  const int o = blockIdx.x, t = threadIdx.x;
  float s = 0.f, q = 0.f;
  for (int r = t; r < GD; r += 256) {
    s += p1[(size_t)r * 128 + o];
    q += p1[(size_t)r * 128 + 64 + o];
  }
  rs[t] = s; rq[t] = q;
  __syncthreads();
  for (int off = 128; off > 0; off >>= 1) {
    if (t < off) { rs[t] += rs[t + off]; rq[t] += rq[t + off]; }
    __syncthreads();
  }
  if (t == 0) {
    const float invN = 1.f / (float)NEDGE;
    float mean = rs[0] * invN;
    float var = rq[0] * invN - mean * mean;
    float sc = g1[o] * rsqrtf(var + EPSV);
    st1[o] = sc;
    st1[O + o] = b1[o] - mean * sc;
  }
}

// ---------------- finalize: pick max/min by scale sign, affine + leaky ----------------
__global__ void k_final(const float* __restrict__ st1, const float* __restrict__ zmin,
                        float* __restrict__ out) {
  int i = blockIdx.x * blockDim.x + threadIdx.x;
  if (i < Q * O) {
    int o = i & 63;
    float sc = st1[o], sh = st1[O + o];
    float base = (sc >= 0.f) ? out[i] : zmin[i];   // out currently holds zmax
    float v = base * sc + sh;
    out[i] = LEAKY(v);
  }
}

extern "C" void kernel_launch(void* const* d_in, const int* in_sizes, int n_in,
                              void* d_out, int out_size, void* d_ws, size_t ws_size,
                              hipStream_t stream) {
  const float* qpts = (const float*)d_in[0];
  const float* spts = (const float*)d_in[1];
  const float* feat = (const float*)d_in[2];
  const int*   inds = (const int*)d_in[3];
  const float* w0   = (const float*)d_in[4];
  const float* g0   = (const float*)d_in[5];
  const float* b0   = (const float*)d_in[6];
  const float* w1   = (const float*)d_in[7];
  const float* g1   = (const float*)d_in[8];
  const float* b1   = (const float*)d_in[9];
  float* out = (float*)d_out;

  char* ws = (char*)d_ws;
  int*   cnt  = (int*)(ws + CNT_OFF);
  int*   ctr  = (int*)(ws + CTR_OFF);
  float* p0   = (float*)(ws + P0_OFF);
  float* st0  = (float*)(ws + ST0_OFF);
  float* zmin = (float*)(ws + ZMIN_OFF);
  float* p1   = (float*)(ws + P1_OFF);
  float* st1  = (float*)(ws + ST1_OFF);
  short* w0f  = (short*)(ws + W0F_OFF);
  short* w1f  = (short*)(ws + W1F_OFF);

  hipMemsetAsync(ws, 0, CTR_OFF + 64, stream);   // cnt + ticket counters
  k_prep_hist<<<520, 256, 0, stream>>>(w0, w1, w0f, w1f, inds, cnt);
  k_hsq<<<GH, 256, 0, stream>>>(feat, cnt, w0f, p0, ctr, g0, b0, st0);
  k_main<<<GD, 256, 0, stream>>>(qpts, spts, feat, inds, w0f, w1f, st0, out, zmin, p1);
  k_red1<<<64, 256, 0, stream>>>(p1, g1, b1, st1);
  k_final<<<(Q * O) / 256, 256, 0, stream>>>(st1, zmin, out);
}

// Round 6
// 86.667 us; speedup vs baseline: 1.1152x; 1.0921x over previous
//
#include <hip/hip_runtime.h>
#include <hip/hip_bf16.h>

typedef __attribute__((ext_vector_type(8))) short bf16x8;
typedef __attribute__((ext_vector_type(4))) short bf16x4;
typedef __attribute__((ext_vector_type(4))) float f32x4;

constexpr int Q = 16384, S = 16384, KNN = 32, F = 64, O = 64;
constexpr int NEDGE = Q * KNN;
constexpr int QB = 8;                   // q's per main block
constexpr int EB = 256;                 // edges per block
constexpr int GD = Q / QB;              // 2048 main blocks
constexpr int GH = 256;                 // k_hsq blocks (64 s each)
constexpr int FP = 72;                  // padded bf16 H row (144B stride)
constexpr float EPSV = 1e-5f;

// workspace byte offsets
constexpr size_t CNT_OFF   = 0;                                   // S ints
constexpr size_t CTR_OFF   = 65536;                               // ticket counters (64B)
constexpr size_t P0_OFF    = 65600;                               // GH*128 f32
constexpr size_t ST0_OFF   = P0_OFF + (size_t)GH * 128 * 4;       // 128 f32
constexpr size_t ZMIN_OFF  = ST0_OFF + 512;                       // Q*O f32
constexpr size_t P1T_OFF   = ZMIN_OFF + (size_t)Q * O * 4;        // 128*GD f32 (transposed)
constexpr size_t ST1_OFF   = P1T_OFF + (size_t)128 * GD * 4;      // 128 f32
constexpr size_t W0F_OFF   = ST1_OFF + 512;                       // 8*64*8 bf16
constexpr size_t W1F_OFF   = W0F_OFF + 8192;                      // 24*64*8 bf16
constexpr size_t FEATB_OFF = W1F_OFF + 24576;                     // S*F bf16 (2MB)

__device__ __forceinline__ short f2bf(float f) {
  __hip_bfloat16 h = __float2bfloat16(f);
  short r; __builtin_memcpy(&r, &h, 2); return r;
}

// ---- fused prep: blocks 0-7 weight frags | 8-71 feat->bf16 | 72-135 LDS histogram ----
__global__ void k_prep_hist(const float* __restrict__ w0g, const float* __restrict__ w1g,
                            short* __restrict__ w0f, short* __restrict__ w1f,
                            const float* __restrict__ feat, short* __restrict__ featb,
                            const int* __restrict__ inds, int* __restrict__ cnt) {
  __shared__ int lh[S];   // 64KB, used only by hist blocks
  const int bx = blockIdx.x, tt = threadIdx.x;
  if (bx < 8) {
    const int t = bx * 256 + tt;   // 2048 entries
    const int fa = t >> 6, ln = t & 63;
    const int l4 = ln >> 4, l15 = ln & 15;
    if (fa < 8) {
      // W0 A-frags: A[m=o][k=f]; frag (mt,kk): o=16mt+l15, f=32kk+8l4
      const int mt = fa >> 1, kk = fa & 1;
      const int o = 16 * mt + l15, f = 32 * kk + 8 * l4;
      const float* src = w0g + o * 64 + f;
      bf16x8 pk;
#pragma unroll
      for (int j = 0; j < 8; ++j) pk[j] = f2bf(src[j]);
      *(bf16x8*)&w0f[t * 8] = pk;
    } else {
      // W1 B-frags: B[k=op][n=c], c=i*64+o; frag nt=i*4+b: o=16b+l15, op=32kk+8l4
      const int fb = fa - 8;                 // 0..23
      const int nt = fb >> 1, kk = fb & 1;
      const int i = nt >> 2, b = nt & 3;
      const int o = 16 * b + l15, op = 32 * kk + 8 * l4;
      const float* src = w1g + (o * 3 + i) * 64 + op;
      bf16x8 pk;
#pragma unroll
      for (int j = 0; j < 8; ++j) pk[j] = f2bf(src[j]);
      *(bf16x8*)&w1f[(fb * 64 + ln) * 8] = pk;
    }
  } else if (bx < 72) {
    // feat f32 -> bf16, 16384 elems per block, coalesced
    const int base = (bx - 8) * 16384;
#pragma unroll
    for (int j = 0; j < 8; ++j) {
      const int i = base + j * 2048 + tt * 8;
      f32x4 a = *(const f32x4*)(feat + i);
      f32x4 b = *(const f32x4*)(feat + i + 4);
      bf16x8 pk;
      pk[0] = f2bf(a[0]); pk[1] = f2bf(a[1]); pk[2] = f2bf(a[2]); pk[3] = f2bf(a[3]);
      pk[4] = f2bf(b[0]); pk[5] = f2bf(b[1]); pk[6] = f2bf(b[2]); pk[7] = f2bf(b[3]);
      *(bf16x8*)(featb + i) = pk;
    }
  } else {
    // LDS-privatized histogram: 64 blocks x 8192 edges
    for (int c = tt; c < S; c += 256) lh[c] = 0;
    __syncthreads();
    const int4* ip = (const int4*)inds;
    const int base = (bx - 72) * 2048;
#pragma unroll
    for (int j = 0; j < 8; ++j) {
      const int4 v = ip[base + j * 256 + tt];
      if (v.x < S) atomicAdd(&lh[v.x], 1);
      if (v.y < S) atomicAdd(&lh[v.y], 1);
      if (v.z < S) atomicAdd(&lh[v.z], 1);
      if (v.w < S) atomicAdd(&lh[v.w], 1);
    }
    __syncthreads();
    for (int c = tt; c < S; c += 256) {
      const int v = lh[c];
      if (v) atomicAdd(&cnt[c], v);
    }
  }
}

// ---- BN0 stats via MFMA (h bitwise == k_main's) + fused last-block reduce -> st0 ----
__global__ void k_hsq(const short* __restrict__ featb, const int* __restrict__ cnt,
                      const short* __restrict__ w0f, float* __restrict__ p0,
                      int* __restrict__ ctr, const float* __restrict__ g0,
                      const float* __restrict__ b0, float* __restrict__ st0) {
  __shared__ float sred[4][2][64];
  __shared__ int isLast;
  const int t = threadIdx.x, blk = blockIdx.x;
  const int wv = t >> 6, ln = t & 63, l4 = ln >> 4, l15 = ln & 15;

  const bf16x8* w0v = (const bf16x8*)w0f;
  bf16x8 w0a[8];
#pragma unroll
  for (int fa = 0; fa < 8; ++fa) w0a[fa] = w0v[fa * 64 + ln];

  const int s0 = blk * 64 + wv * 16;
  const float wc = (float)cnt[s0 + l15];
  const short* fb = featb + (size_t)(s0 + l15) * F + 8 * l4;
  const bf16x8 y0 = *(const bf16x8*)(fb);
  const bf16x8 y1 = *(const bf16x8*)(fb + 32);

  float hs[4][4], hq[4][4];
#pragma unroll
  for (int mt = 0; mt < 4; ++mt) {
    f32x4 acc = {0.f, 0.f, 0.f, 0.f};
    acc = __builtin_amdgcn_mfma_f32_16x16x32_bf16(w0a[2 * mt], y0, acc, 0, 0, 0);
    acc = __builtin_amdgcn_mfma_f32_16x16x32_bf16(w0a[2 * mt + 1], y1, acc, 0, 0, 0);
#pragma unroll
    for (int r = 0; r < 4; ++r) {
      const float h = acc[r];
      hs[mt][r] = wc * h;
      hq[mt][r] = wc * h * h;
    }
  }
#pragma unroll
  for (int mt = 0; mt < 4; ++mt)
#pragma unroll
    for (int r = 0; r < 4; ++r) {
      float s = hs[mt][r], q = hq[mt][r];
#pragma unroll
      for (int d = 1; d < 16; d <<= 1) { s += __shfl_xor(s, d); q += __shfl_xor(q, d); }
      hs[mt][r] = s; hq[mt][r] = q;
    }
  if (l15 == 0) {
#pragma unroll
    for (int mt = 0; mt < 4; ++mt)
#pragma unroll
      for (int r = 0; r < 4; ++r) {
        const int o = 16 * mt + 4 * l4 + r;
        sred[wv][0][o] = hs[mt][r];
        sred[wv][1][o] = hq[mt][r];
      }
  }
  __syncthreads();
  if (t < 128) {
    const int qq = t >> 6, o = t & 63;
    p0[(size_t)blk * 128 + t] =
        sred[0][qq][o] + sred[1][qq][o] + sred[2][qq][o] + sred[3][qq][o];
  }
  // last-block reduction -> st0 (deterministic fixed order)
  __syncthreads();
  __threadfence();
  if (t == 0) isLast = (atomicAdd(&ctr[0], 1) == GH - 1);
  __syncthreads();
  if (isLast) {
    __threadfence();
    if (t < O) {
      float s = 0.f, q = 0.f;
      for (int b = 0; b < GH; ++b) {
        s += p0[(size_t)b * 128 + t];
        q += p0[(size_t)b * 128 + 64 + t];
      }
      const float invN = 1.f / (float)NEDGE;
      const float mean = s * invN;
      const float var = q * invN - mean * mean;
      const float sc = g0[t] * rsqrtf(var + EPSV);
      st0[t] = sc;
      st0[O + t] = b0[t] - mean * sc;
    }
  }
}

// ---- main MFMA pass: bf16 direct gather, batched loads, LDS for H + x only ----
__launch_bounds__(256, 3)
__global__ void k_main(const float* __restrict__ qpts, const float* __restrict__ spts,
                       const short* __restrict__ featb, const int* __restrict__ inds,
                       const short* __restrict__ w0f, const short* __restrict__ w1f,
                       const float* __restrict__ st0,
                       float* __restrict__ zmax, float* __restrict__ zmin,
                       float* __restrict__ p1t) {
  __shared__ __align__(16) short hbuf[EB * FP];   // H, [e][72] bf16
  __shared__ __align__(16) float xs[3 * EB];      // x per edge; first 512 reused as swred

  const int t = threadIdx.x, blk = blockIdx.x;
  const int wv = t >> 6, ln = t & 63, l4 = ln >> 4, l15 = ln & 15;
  const int ebase = blk * EB;

  // ---- stage x (wave-local rows; same-wave DS ordering, no barrier needed)
  {
    const int e = t;
    const int idx = inds[ebase + e];
    const int q = blk * QB + (e >> 5);
    float x0 = 0.f, x1 = 0.f, x2 = 0.f;
    if (idx < S) {
      x0 = spts[idx * 3 + 0] - qpts[q * 3 + 0];
      x1 = spts[idx * 3 + 1] - qpts[q * 3 + 1];
      x2 = spts[idx * 3 + 2] - qpts[q * 3 + 2];
    }
    xs[0 * EB + e] = x0; xs[1 * EB + e] = x1; xs[2 * EB + e] = x2;
  }

  // W0 A-frags (L2-hot, coalesced)
  const bf16x8* w0v = (const bf16x8*)w0f;
  bf16x8 w0a[8];
#pragma unroll
  for (int fa = 0; fa < 8; ++fa) w0a[fa] = w0v[fa * 64 + ln];

  // ---- Phase A: batch-load all idx, then all Y frags (one latency round)
  int idxr[4];
#pragma unroll
  for (int nt = 0; nt < 4; ++nt) idxr[nt] = inds[ebase + wv * 64 + nt * 16 + l15];

  bf16x8 yv[4][2];
#pragma unroll
  for (int nt = 0; nt < 4; ++nt) {
    if (idxr[nt] < S) {
      const short* fb = featb + (size_t)idxr[nt] * F + 8 * l4;
      yv[nt][0] = *(const bf16x8*)(fb);
      yv[nt][1] = *(const bf16x8*)(fb + 32);
    } else {
#pragma unroll
      for (int j = 0; j < 8; ++j) { yv[nt][0][j] = 0; yv[nt][1][j] = 0; }
    }
  }

  // BN0 scale/shift regs: o = 16mt + 4*l4 + r
  float scr[4][4], shr[4][4];
#pragma unroll
  for (int mt = 0; mt < 4; ++mt)
#pragma unroll
    for (int r = 0; r < 4; ++r) {
      const int o = 16 * mt + 4 * l4 + r;
      scr[mt][r] = st0[o]; shr[mt][r] = st0[O + o];
    }

#pragma unroll
  for (int nt = 0; nt < 4; ++nt) {
    const int erow = wv * 64 + nt * 16 + l15;
#pragma unroll
    for (int mt = 0; mt < 4; ++mt) {
      f32x4 acc = {0.f, 0.f, 0.f, 0.f};
      acc = __builtin_amdgcn_mfma_f32_16x16x32_bf16(w0a[2 * mt], yv[nt][0], acc, 0, 0, 0);
      acc = __builtin_amdgcn_mfma_f32_16x16x32_bf16(w0a[2 * mt + 1], yv[nt][1], acc, 0, 0, 0);
      bf16x4 hv;
#pragma unroll
      for (int r = 0; r < 4; ++r) {
        float v = acc[r] * scr[mt][r] + shr[mt][r];
        v = fmaxf(v, 0.1f * v);               // leaky
        hv[r] = f2bf(v);
      }
      *(bf16x4*)&hbuf[erow * FP + 16 * mt + 4 * l4] = hv;
    }
  }

  // ---- Phase B operand prefetch (wave-local H rows; same-wave DS ordering)
  bf16x8 hA[4][2];
#pragma unroll
  for (int mt = 0; mt < 4; ++mt) {
    const int erow = wv * 64 + mt * 16 + l15;
    hA[mt][0] = *(const bf16x8*)&hbuf[erow * FP + 8 * l4];
    hA[mt][1] = *(const bf16x8*)&hbuf[erow * FP + 32 + 8 * l4];
  }

  const bf16x8* w1v = (const bf16x8*)w1f;
  float zmx[2][4], zmn[2][4], zs[4], zq[4];
#pragma unroll
  for (int j = 0; j < 4; ++j) {
    zs[j] = 0.f; zq[j] = 0.f;
    zmx[0][j] = -3.4e38f; zmx[1][j] = -3.4e38f;
    zmn[0][j] = 3.4e38f;  zmn[1][j] = 3.4e38f;
  }

  // ---- Phase B: D2[e][c=i*64+o] = H * W1p ; combine with x ; stats
#pragma unroll
  for (int b = 0; b < 4; ++b) {
    bf16x8 w1b[6];
#pragma unroll
    for (int i = 0; i < 3; ++i)
#pragma unroll
      for (int kk = 0; kk < 2; ++kk)
        w1b[i * 2 + kk] = w1v[(((i * 4 + b) * 2) + kk) * 64 + ln];
#pragma unroll
    for (int mt = 0; mt < 4; ++mt) {
      const int ex = wv * 64 + mt * 16 + 4 * l4;
      f32x4 z4 = {0.f, 0.f, 0.f, 0.f};
#pragma unroll
      for (int i = 0; i < 3; ++i) {
        f32x4 acc = {0.f, 0.f, 0.f, 0.f};
        acc = __builtin_amdgcn_mfma_f32_16x16x32_bf16(hA[mt][0], w1b[2 * i], acc, 0, 0, 0);
        acc = __builtin_amdgcn_mfma_f32_16x16x32_bf16(hA[mt][1], w1b[2 * i + 1], acc, 0, 0, 0);
        const f32x4 xv = *(const f32x4*)&xs[i * EB + ex];
#pragma unroll
        for (int r = 0; r < 4; ++r) z4[r] += acc[r] * xv[r];
      }
      const int qh = mt >> 1;
#pragma unroll
      for (int r = 0; r < 4; ++r) {
        const float v = z4[r];
        zmx[qh][b] = fmaxf(zmx[qh][b], v);
        zmn[qh][b] = fminf(zmn[qh][b], v);
        zs[b] += v; zq[b] += v * v;
      }
    }
  }

  // ---- cross-group (l4) reductions: lanes l, l^16, l^32 share o
#pragma unroll
  for (int qh = 0; qh < 2; ++qh)
#pragma unroll
    for (int b = 0; b < 4; ++b) {
      float m = zmx[qh][b];
      m = fmaxf(m, __shfl_xor(m, 16)); m = fmaxf(m, __shfl_xor(m, 32));
      zmx[qh][b] = m;
      float n = zmn[qh][b];
      n = fminf(n, __shfl_xor(n, 16)); n = fminf(n, __shfl_xor(n, 32));
      zmn[qh][b] = n;
    }
#pragma unroll
  for (int b = 0; b < 4; ++b) {
    float s = zs[b];  s += __shfl_xor(s, 16);  s += __shfl_xor(s, 32);  zs[b] = s;
    float sq = zq[b]; sq += __shfl_xor(sq, 16); sq += __shfl_xor(sq, 32); zq[b] = sq;
  }

  if (l4 == 0) {
#pragma unroll
    for (int qh = 0; qh < 2; ++qh) {
      const int q = blk * QB + wv * 2 + qh;
#pragma unroll
      for (int b = 0; b < 4; ++b) {
        zmax[(size_t)q * O + 16 * b + l15] = zmx[qh][b];
        zmin[(size_t)q * O + 16 * b + l15] = zmn[qh][b];
      }
    }
  }

  // ---- block sum partials: reuse xs[0..511] as swred (barrier guards the union)
  __syncthreads();
  if (l4 == 0) {
#pragma unroll
    for (int b = 0; b < 4; ++b) {
      xs[wv * 128 + 16 * b + l15] = zs[b];
      xs[wv * 128 + 64 + 16 * b + l15] = zq[b];
    }
  }
  __syncthreads();
  if (t < 128)
    p1t[(size_t)t * GD + blk] = xs[t] + xs[128 + t] + xs[256 + t] + xs[384 + t];
}

// ---- reduce z stats (coalesced, transposed p1) + BN1 scale/shift ----
__global__ void k_red1(const float* __restrict__ p1t, const float* __restrict__ g1,
                       const float* __restrict__ b1, float* __restrict__ st1) {
  __shared__ float rs[256], rq[256];
  const int o = blockIdx.x, t = threadIdx.x;
  const float* ps = p1t + (size_t)o * GD;
  const float* pq = p1t + (size_t)(64 + o) * GD;
  float s = 0.f, q = 0.f;
#pragma unroll
  for (int j = 0; j < GD / 256; ++j) {
    s += ps[j * 256 + t];
    q += pq[j * 256 + t];
  }
  rs[t] = s; rq[t] = q;
  __syncthreads();
  for (int off = 128; off > 0; off >>= 1) {
    if (t < off) { rs[t] += rs[t + off]; rq[t] += rq[t + off]; }
    __syncthreads();
  }
  if (t == 0) {
    const float invN = 1.f / (float)NEDGE;
    const float mean = rs[0] * invN;
    const float var = rq[0] * invN - mean * mean;
    const float sc = g1[o] * rsqrtf(var + EPSV);
    st1[o] = sc;
    st1[O + o] = b1[o] - mean * sc;
  }
}

// ---- finalize: pick max/min by scale sign, affine + leaky (vectorized) ----
__global__ void k_final(const float* __restrict__ st1, const float* __restrict__ zmin,
                        float* __restrict__ out) {
  const int i4 = blockIdx.x * blockDim.x + threadIdx.x;   // Q*O/4 elements
  const int o0 = (i4 * 4) & 63;
  const f32x4 mx = *(const f32x4*)(out + (size_t)i4 * 4);   // holds zmax
  const f32x4 mn = *(const f32x4*)(zmin + (size_t)i4 * 4);
  const f32x4 sc = *(const f32x4*)(st1 + o0);
  const f32x4 sh = *(const f32x4*)(st1 + O + o0);
  f32x4 r;
#pragma unroll
  for (int j = 0; j < 4; ++j) {
    const float base = (sc[j] >= 0.f) ? mx[j] : mn[j];
    const float v = base * sc[j] + sh[j];
    r[j] = fmaxf(v, 0.1f * v);
  }
  *(f32x4*)(out + (size_t)i4 * 4) = r;
}

extern "C" void kernel_launch(void* const* d_in, const int* in_sizes, int n_in,
                              void* d_out, int out_size, void* d_ws, size_t ws_size,
                              hipStream_t stream) {
  const float* qpts = (const float*)d_in[0];
  const float* spts = (const float*)d_in[1];
  const float* feat = (const float*)d_in[2];
  const int*   inds = (const int*)d_in[3];
  const float* w0   = (const float*)d_in[4];
  const float* g0   = (const float*)d_in[5];
  const float* b0   = (const float*)d_in[6];
  const float* w1   = (const float*)d_in[7];
  const float* g1   = (const float*)d_in[8];
  const float* b1   = (const float*)d_in[9];
  float* out = (float*)d_out;

  char* ws = (char*)d_ws;
  int*   cnt   = (int*)(ws + CNT_OFF);
  int*   ctr   = (int*)(ws + CTR_OFF);
  float* p0    = (float*)(ws + P0_OFF);
  float* st0   = (float*)(ws + ST0_OFF);
  float* zmin  = (float*)(ws + ZMIN_OFF);
  float* p1t   = (float*)(ws + P1T_OFF);
  float* st1   = (float*)(ws + ST1_OFF);
  short* w0f   = (short*)(ws + W0F_OFF);
  short* w1f   = (short*)(ws + W1F_OFF);
  short* featb = (short*)(ws + FEATB_OFF);

  hipMemsetAsync(ws, 0, CTR_OFF + 64, stream);   // cnt + ticket counters
  k_prep_hist<<<136, 256, 0, stream>>>(w0, w1, w0f, w1f, feat, featb, inds, cnt);
  k_hsq<<<GH, 256, 0, stream>>>(featb, cnt, w0f, p0, ctr, g0, b0, st0);
  k_main<<<GD, 256, 0, stream>>>(qpts, spts, featb, inds, w0f, w1f, st0, out, zmin, p1t);
  k_red1<<<64, 256, 0, stream>>>(p1t, g1, b1, st1);
  k_final<<<(Q * O) / 1024, 256, 0, stream>>>(st1, zmin, out);
}